// Round 1
// baseline (392.559 us; speedup 1.0000x reference)
//
#include <hip/hip_runtime.h>
#include <hip/hip_bf16.h>

#define IN_C  128
#define HID_C 64
#define OUT_C 32
#define NEG_SLOPE 0.2f

// ---------------------------------------------------------------------------
// Kernel 1: zero a float region (grid-stride)
// ---------------------------------------------------------------------------
__global__ void zero_kernel(float* __restrict__ p, long n) {
    long i = (long)blockIdx.x * blockDim.x + threadIdx.x;
    long stride = (long)gridDim.x * blockDim.x;
    for (; i < n; i += stride) p[i] = 0.0f;
}

// ---------------------------------------------------------------------------
// Kernel 2: h = x @ W  (per node), plus a_src = h . att_src, a_dst = h . att_dst
// One wave (64 lanes) per node; lane c computes h[node][c].
// Block = 256 threads = 4 nodes. Grid must be exact (N divisible by 4 -> ok,
// but guarded with all-threads-reach-barrier structure anyway).
// ---------------------------------------------------------------------------
__global__ __launch_bounds__(256) void node_gemm_kernel(
    const float* __restrict__ x, const float* __restrict__ W,
    const float* __restrict__ att_src, const float* __restrict__ att_dst,
    float* __restrict__ h, float* __restrict__ a_src, float* __restrict__ a_dst,
    int n_nodes)
{
    __shared__ float xs[4][IN_C];
    const int wv   = threadIdx.x >> 6;
    const int lane = threadIdx.x & 63;
    const int node = blockIdx.x * 4 + wv;
    const bool valid = node < n_nodes;

    if (valid) {
        const float* xr = x + (long)node * IN_C;
        xs[wv][lane]      = xr[lane];
        xs[wv][lane + 64] = xr[lane + 64];
    }
    __syncthreads();

    if (!valid) return;

    float acc = 0.0f;
#pragma unroll
    for (int k = 0; k < IN_C; ++k)
        acc = fmaf(xs[wv][k], W[k * HID_C + lane], acc);

    h[(long)node * HID_C + lane] = acc;

    // wave-level reductions for attention logits
    float vs = acc * att_src[lane];
    float vd = acc * att_dst[lane];
#pragma unroll
    for (int off = 32; off > 0; off >>= 1) {
        vs += __shfl_xor(vs, off, 64);
        vd += __shfl_xor(vd, off, 64);
    }
    if (lane == 0) {
        a_src[node] = vs;
        a_dst[node] = vd;
    }
}

// ---------------------------------------------------------------------------
// Kernel 3: per-edge exp(leaky_relu(logit)) and denominator accumulation.
// Edges i in [0,E) are real edges; i in [E, E+N) are self-loops (s=d=i-E).
// Note: max-subtraction is skipped (mathematically identical softmax; logits
// are bounded ~|6| so exp cannot overflow).
// ---------------------------------------------------------------------------
__global__ void edge_exp_kernel(
    const int* __restrict__ ei, int E, int n_nodes,
    const float* __restrict__ a_src, const float* __restrict__ a_dst,
    float* __restrict__ w, float* __restrict__ denom)
{
    long i = (long)blockIdx.x * blockDim.x + threadIdx.x;
    long total = (long)E + n_nodes;
    if (i >= total) return;
    int s, d;
    if (i < E) { s = ei[i]; d = ei[E + i]; }
    else       { s = d = (int)(i - E); }
    float e = a_src[s] + a_dst[d];
    e = (e >= 0.0f) ? e : NEG_SLOPE * e;
    float ww = expf(e);
    w[i] = ww;
    atomicAdd(denom + d, ww);
}

// ---------------------------------------------------------------------------
// Kernel 4: scatter messages. One wave per edge (lane c handles channel c).
// agg[d][c] += (w[i]/denom[d]) * h[s][c]
// ---------------------------------------------------------------------------
__global__ __launch_bounds__(256) void scatter_kernel(
    const int* __restrict__ ei, int E, int n_nodes,
    const float* __restrict__ w, const float* __restrict__ denom,
    const float* __restrict__ h, float* __restrict__ agg)
{
    const int lane = threadIdx.x & 63;
    const int wv   = threadIdx.x >> 6;
    long i = (long)blockIdx.x * 4 + wv;
    long total = (long)E + n_nodes;
    if (i >= total) return;
    int s, d;
    if (i < E) { s = ei[i]; d = ei[E + i]; }
    else       { s = d = (int)(i - E); }
    float alpha = w[i] / (denom[d] + 1e-16f);
    atomicAdd(agg + (long)d * HID_C + lane, alpha * h[(long)s * HID_C + lane]);
}

// ---------------------------------------------------------------------------
// Kernel 5: out = relu(agg + bias_conv) @ W_lin + b_lin
// One wave per node; lane c holds relu value for channel c, round-trip
// through LDS, lanes 0..31 compute the 32 outputs.
// ---------------------------------------------------------------------------
__global__ __launch_bounds__(256) void final_kernel(
    const float* __restrict__ agg, const float* __restrict__ bias_conv,
    const float* __restrict__ W_lin, const float* __restrict__ b_lin,
    float* __restrict__ out, int n_nodes)
{
    __shared__ float v[4][HID_C];
    const int wv   = threadIdx.x >> 6;
    const int lane = threadIdx.x & 63;
    const int node = blockIdx.x * 4 + wv;
    const bool valid = node < n_nodes;

    float val = 0.0f;
    if (valid) {
        val = agg[(long)node * HID_C + lane] + bias_conv[lane];
        val = (val > 0.0f) ? val : 0.0f;
    }
    v[wv][lane] = val;
    __syncthreads();

    if (valid && lane < OUT_C) {
        float acc = b_lin[lane];
#pragma unroll
        for (int c = 0; c < HID_C; ++c)
            acc = fmaf(v[wv][c], W_lin[c * OUT_C + lane], acc);
        out[(long)node * OUT_C + lane] = acc;
    }
}

// ---------------------------------------------------------------------------
extern "C" void kernel_launch(void* const* d_in, const int* in_sizes, int n_in,
                              void* d_out, int out_size, void* d_ws, size_t ws_size,
                              hipStream_t stream) {
    const float* x         = (const float*)d_in[0];
    const int*   ei        = (const int*)d_in[1];   // [2,E] int32 (harness converts)
    const float* W         = (const float*)d_in[2];
    const float* att_src   = (const float*)d_in[3];
    const float* att_dst   = (const float*)d_in[4];
    const float* bias_conv = (const float*)d_in[5];
    const float* W_lin     = (const float*)d_in[6];
    const float* b_lin     = (const float*)d_in[7];
    float*       out       = (float*)d_out;

    const int n_nodes = in_sizes[0] / IN_C;     // 50000
    const int E       = in_sizes[1] / 2;        // 800000
    const long total_edges = (long)E + n_nodes; // incl. self loops

    // workspace layout (floats)
    float* ws    = (float*)d_ws;
    float* h     = ws;                                   // N*64
    float* a_src = h     + (long)n_nodes * HID_C;        // N
    float* a_dst = a_src + n_nodes;                      // N
    float* w     = a_dst + n_nodes;                      // E+N
    float* agg   = w     + total_edges;                  // N*64   } contiguous
    float* denom = agg   + (long)n_nodes * HID_C;        // N      } zero range

    // 1) zero agg + denom (contiguous)
    {
        long nz = (long)n_nodes * HID_C + n_nodes;
        int blocks = (int)((nz + 1023) / 1024);
        if (blocks > 4096) blocks = 4096;
        zero_kernel<<<blocks, 1024, 0, stream>>>(agg, nz);
    }

    // 2) h = x@W, attention logits
    {
        int grid = (n_nodes + 3) / 4;
        node_gemm_kernel<<<grid, 256, 0, stream>>>(x, W, att_src, att_dst,
                                                   h, a_src, a_dst, n_nodes);
    }

    // 3) edge exp + denom
    {
        int grid = (int)((total_edges + 255) / 256);
        edge_exp_kernel<<<grid, 256, 0, stream>>>(ei, E, n_nodes, a_src, a_dst,
                                                  w, denom);
    }

    // 4) scatter messages
    {
        int grid = (int)((total_edges + 3) / 4);
        scatter_kernel<<<grid, 256, 0, stream>>>(ei, E, n_nodes, w, denom, h, agg);
    }

    // 5) epilogue linear
    {
        int grid = (n_nodes + 3) / 4;
        final_kernel<<<grid, 256, 0, stream>>>(agg, bias_conv, W_lin, b_lin,
                                               out, n_nodes);
    }
}